// Round 3
// baseline (26.780 us; speedup 1.0000x reference)
//
#include <hip/hip_runtime.h>

// out[b,d] = sum_c w[b,c] * f[idx[b,c,0],d] * f[idx[b,c,1],d]   (w==0 -> padding, tail-contiguous)
// fallback: out[b,:] = f[target_nodes[b],:] when has_edge[b] <= 0
//
// Layout:
//  - one 64-lane wave per output row b; each lane holds float2 (D=128 floats)
//  - 256-thread block = 4 waves = 4 rows; no syncthreads
//  - per-row combo count via wave ballot, then branch-free counted loop
//  - gather dedup: combos from card-2 edges are [t,a]/[a,t] or [a,a]; reuse the
//    preloaded target row f[t] and fold ix.x==ix.y into a single gather.
//    Cuts gathered rows ~33% (we're cache-BW bound on gathers).

__global__ __launch_bounds__(256) void tmp_aggregate_kernel(
    const float*  __restrict__ features,      // [N, 128]
    const int*    __restrict__ target_nodes,  // [B]
    const int*    __restrict__ comb_idx,      // [B, cmax, 2]
    const float*  __restrict__ comb_w,        // [B, cmax]
    const float*  __restrict__ has_edge,      // [B]
    float*        __restrict__ out,           // [B, 128]
    int B, int cmax)
{
    const int lane = threadIdx.x & 63;
    const int wave = __builtin_amdgcn_readfirstlane((int)(threadIdx.x >> 6));
    const int b = blockIdx.x * 4 + wave;
    if (b >= B) return;

    const float2* __restrict__ f2 = (const float2*)features;
    const long base = (long)b * cmax;

    // target row: needed for fallback AND for dedup of [t,a] combos
    const int tnode = target_nodes[b];
    const float2 ft = f2[(long)tnode * 64 + lane];

    // --- count live combos (w != 0), padding is tail-contiguous ---
    int cnt = 0;
    for (int c0 = 0; c0 < cmax; c0 += 64) {
        const int c = c0 + lane;
        const float w = (c < cmax) ? comb_w[base + c] : 0.0f;
        const unsigned long long m = __ballot(w != 0.0f);
        cnt += __popcll(m);
        if (m != ~0ull) break;
    }

    // --- main loop: wave-uniform case split saves gathers ---
    float2 acc = make_float2(0.f, 0.f);
    const int2* __restrict__ idx2 = (const int2*)comb_idx;

    #pragma unroll 2
    for (int c = 0; c < cnt; ++c) {
        const float w  = comb_w[base + c];
        const int2  ix = idx2[base + c];

        float2 x, y;
        if (ix.x == ix.y) {                       // [a,a] combo: one gather
            y = f2[(long)ix.y * 64 + lane];
            x = y;
        } else if (ix.x == tnode) {               // [t,a]: reuse preloaded ft
            y = f2[(long)ix.y * 64 + lane];
            x = ft;
        } else if (ix.y == tnode) {               // [a,t]: reuse preloaded ft
            x = f2[(long)ix.x * 64 + lane];
            y = ft;
        } else {                                  // card-3 combo [u,v]
            x = f2[(long)ix.x * 64 + lane];
            y = f2[(long)ix.y * 64 + lane];
        }

        acc.x = fmaf(w * x.x, y.x, acc.x);
        acc.y = fmaf(w * x.y, y.y, acc.y);
    }

    if (!(has_edge[b] > 0.f)) {
        acc = ft;
    }

    __builtin_nontemporal_store(acc.x, &out[(long)b * 128 + lane * 2 + 0]);
    __builtin_nontemporal_store(acc.y, &out[(long)b * 128 + lane * 2 + 1]);
}

extern "C" void kernel_launch(void* const* d_in, const int* in_sizes, int n_in,
                              void* d_out, int out_size, void* d_ws, size_t ws_size,
                              hipStream_t stream) {
    const float* features     = (const float*)d_in[0];
    const int*   target_nodes = (const int*)d_in[1];
    const int*   comb_idx     = (const int*)d_in[2];
    const float* comb_w       = (const float*)d_in[3];
    const float* has_edge     = (const float*)d_in[4];
    float*       out          = (float*)d_out;

    const int B    = in_sizes[1];                 // 16384
    const int cmax = in_sizes[2] / (B * 2);       // combos per row (padded)

    const int rows_per_block = 4;                 // 4 waves x 1 row
    const int grid = (B + rows_per_block - 1) / rows_per_block;

    tmp_aggregate_kernel<<<grid, 256, 0, stream>>>(
        features, target_nodes, comb_idx, comb_w, has_edge, out, B, cmax);
}

// Round 4
// 24.110 us; speedup vs baseline: 1.1107x; 1.1107x over previous
//
#include <hip/hip_runtime.h>

// out[b,d] = sum_c w[b,c] * f[idx[b,c,0],d] * f[idx[b,c,1],d]   (w==0 -> padding, tail-contiguous)
// fallback: out[b,:] = f[target_nodes[b],:] when has_edge[b] <= 0
//
// Layout:
//  - one 64-lane wave per output row b; lane owns float2 (D=128)
//  - 256-thread block = 4 waves = 4 rows; no syncthreads
//  - combo count via one wave ballot, then BRANCH-FREE counted loop (round-2 win)
//  - branch-free dedup: combos containing the target node redirect that gather's
//    ADDRESS at the partner row (same-iteration duplicate -> L1 hit) and recover
//    f[t] via select. No exec-mask divergence, pipelining preserved.

__global__ __launch_bounds__(256) void tmp_aggregate_kernel(
    const float*  __restrict__ features,      // [N, 128]
    const int*    __restrict__ target_nodes,  // [B]
    const int*    __restrict__ comb_idx,      // [B, cmax, 2]
    const float*  __restrict__ comb_w,        // [B, cmax]
    const float*  __restrict__ has_edge,      // [B]
    float*        __restrict__ out,           // [B, 128]
    int B, int cmax)
{
    const int lane = threadIdx.x & 63;
    const int wave = __builtin_amdgcn_readfirstlane((int)(threadIdx.x >> 6));
    const int b = blockIdx.x * 4 + wave;
    if (b >= B) return;

    const float2* __restrict__ f2 = (const float2*)features;
    const long base = (long)b * cmax;

    // target row: fallback + dedup source
    const int tnode = target_nodes[b];
    const float2 ft = f2[(long)tnode * 64 + lane];

    // --- count live combos (w != 0), padding is tail-contiguous ---
    int cnt = 0;
    for (int c0 = 0; c0 < cmax; c0 += 64) {
        const int c = c0 + lane;
        const float w = (c < cmax) ? comb_w[base + c] : 0.0f;
        const unsigned long long m = __ballot(w != 0.0f);
        cnt += __popcll(m);
        if (m != ~0ull) break;
    }

    // --- branch-free main loop, unroll 8 for MLP ---
    float2 acc = make_float2(0.f, 0.f);
    const int2* __restrict__ idx2 = (const int2*)comb_idx;

    #pragma unroll 8
    for (int c = 0; c < cnt; ++c) {
        const float w  = comb_w[base + c];
        const int2  ix = idx2[base + c];

        const bool tx = (ix.x == tnode);
        const bool ty = (ix.y == tnode);
        // redirect target-row gathers at the partner row: duplicate address in the
        // SAME iteration -> L1 hit instead of an L2/L3 round trip for f[t]
        const int ax = tx ? ix.y : ix.x;
        const int ay = ty ? ix.x : ix.y;

        const float2 xl = f2[(long)ax * 64 + lane];
        const float2 yl = f2[(long)ay * 64 + lane];

        const float xx = tx ? ft.x : xl.x;
        const float xy = tx ? ft.y : xl.y;
        const float yx = ty ? ft.x : yl.x;
        const float yy = ty ? ft.y : yl.y;

        acc.x = fmaf(w * xx, yx, acc.x);
        acc.y = fmaf(w * xy, yy, acc.y);
    }

    if (!(has_edge[b] > 0.f)) {
        acc = ft;
    }

    __builtin_nontemporal_store(acc.x, &out[(long)b * 128 + lane * 2 + 0]);
    __builtin_nontemporal_store(acc.y, &out[(long)b * 128 + lane * 2 + 1]);
}

extern "C" void kernel_launch(void* const* d_in, const int* in_sizes, int n_in,
                              void* d_out, int out_size, void* d_ws, size_t ws_size,
                              hipStream_t stream) {
    const float* features     = (const float*)d_in[0];
    const int*   target_nodes = (const int*)d_in[1];
    const int*   comb_idx     = (const int*)d_in[2];
    const float* comb_w       = (const float*)d_in[3];
    const float* has_edge     = (const float*)d_in[4];
    float*       out          = (float*)d_out;

    const int B    = in_sizes[1];                 // 16384
    const int cmax = in_sizes[2] / (B * 2);       // combos per row (padded)

    const int rows_per_block = 4;                 // 4 waves x 1 row
    const int grid = (B + rows_per_block - 1) / rows_per_block;

    tmp_aggregate_kernel<<<grid, 256, 0, stream>>>(
        features, target_nodes, comb_idx, comb_w, has_edge, out, B, cmax);
}

// Round 6
// 22.455 us; speedup vs baseline: 1.1926x; 1.0737x over previous
//
#include <hip/hip_runtime.h>

// out[b,d] = sum_c w[b,c] * f[idx[b,c,0],d] * f[idx[b,c,1],d]   (w==0 -> padding, tail-contiguous)
// fallback: out[b,:] = f[target_nodes[b],:] when has_edge[b] <= 0
//
// Layout (round 5 = round 4 + compile fix):
//  - float4 per lane, 32-lane half-wave per row  => one wave processes TWO rows
//    concurrently: 2x memory-level parallelism, half the VMEM instructions/row,
//    16B/lane coalescing sweet spot. Branch-free counted loop (round-2 win) kept.
//  - shorter half-wave runs to the pair max with w==0 padding (idx==0 -> L1-hot f[0])
//  - nontemporal store via native ext_vector_type (HIP float4 rejected by builtin)

typedef float vfloat4 __attribute__((ext_vector_type(4)));

__global__ __launch_bounds__(256) void tmp_aggregate_kernel(
    const float*  __restrict__ features,      // [N, 128]
    const int*    __restrict__ target_nodes,  // [B]
    const int*    __restrict__ comb_idx,      // [B, cmax, 2]
    const float*  __restrict__ comb_w,        // [B, cmax]
    const float*  __restrict__ has_edge,      // [B]
    float*        __restrict__ out,           // [B, 128]
    int B, int cmax)
{
    const int lane    = threadIdx.x & 63;
    const int wave    = __builtin_amdgcn_readfirstlane((int)(threadIdx.x >> 6));
    const int sub     = lane & 31;            // lane within half-wave
    const int half    = lane >> 5;            // 0 -> row b0, 1 -> row b1
    const int rowbase = (blockIdx.x * 4 + wave) * 2;
    const int b       = rowbase + half;
    if (rowbase >= B) return;                 // B even; both rows valid together

    const vfloat4* __restrict__ f4 = (const vfloat4*)features;
    const long base = (long)b * cmax;

    // --- per-row live-combo count (w != 0), padding is tail-contiguous ---
    int cnt = 0;
    for (int c0 = 0; c0 < cmax; c0 += 32) {
        const int c = c0 + sub;
        const float w = (c < cmax) ? comb_w[base + c] : 0.0f;
        const unsigned long long m = __ballot(w != 0.0f);
        cnt += __popc((unsigned int)(m >> (half * 32)));
        const bool tail0 = ((unsigned int)(m      ) != 0xffffffffu);
        const bool tail1 = ((unsigned int)(m >> 32) != 0xffffffffu);
        if (tail0 && tail1) break;            // both rows found their tail
    }

    // wave-uniform loop bound = max over the two half-waves
    const int cnt_other = __shfl(cnt, lane ^ 32);
    const int loop_n = __builtin_amdgcn_readfirstlane(cnt > cnt_other ? cnt : cnt_other);

    const int tnode = target_nodes[b];
    const vfloat4 ft = f4[(long)tnode * 32 + sub];

    // --- branch-free main loop: 2 rows in flight per wave ---
    vfloat4 acc = {0.f, 0.f, 0.f, 0.f};
    const int2* __restrict__ idx2 = (const int2*)comb_idx;

    #pragma unroll 4
    for (int c = 0; c < loop_n; ++c) {
        const float w  = comb_w[base + c];            // broadcast within half-wave
        const int2  ix = idx2[base + c];
        const vfloat4 x = f4[(long)ix.x * 32 + sub];
        const vfloat4 y = f4[(long)ix.y * 32 + sub];
        acc.x = fmaf(w * x.x, y.x, acc.x);
        acc.y = fmaf(w * x.y, y.y, acc.y);
        acc.z = fmaf(w * x.z, y.z, acc.z);
        acc.w = fmaf(w * x.w, y.w, acc.w);
    }

    const bool fb = !(has_edge[b] > 0.f);
    acc.x = fb ? ft.x : acc.x;
    acc.y = fb ? ft.y : acc.y;
    acc.z = fb ? ft.z : acc.z;
    acc.w = fb ? ft.w : acc.w;

    __builtin_nontemporal_store(acc, &((vfloat4*)out)[(long)b * 32 + sub]);
}

extern "C" void kernel_launch(void* const* d_in, const int* in_sizes, int n_in,
                              void* d_out, int out_size, void* d_ws, size_t ws_size,
                              hipStream_t stream) {
    const float* features     = (const float*)d_in[0];
    const int*   target_nodes = (const int*)d_in[1];
    const int*   comb_idx     = (const int*)d_in[2];
    const float* comb_w       = (const float*)d_in[3];
    const float* has_edge     = (const float*)d_in[4];
    float*       out          = (float*)d_out;

    const int B    = in_sizes[1];                 // 16384
    const int cmax = in_sizes[2] / (B * 2);       // combos per row (padded)

    const int rows_per_block = 8;                 // 4 waves x 2 rows
    const int grid = (B + rows_per_block - 1) / rows_per_block;

    tmp_aggregate_kernel<<<grid, 256, 0, stream>>>(
        features, target_nodes, comb_idx, comb_w, has_edge, out, B, cmax);
}

// Round 7
// 19.843 us; speedup vs baseline: 1.3496x; 1.1317x over previous
//
#include <hip/hip_runtime.h>

// out[b,d] = sum_c w[b,c] * f[idx[b,c,0],d] * f[idx[b,c,1],d]   (w==0 -> padding, tail-contiguous)
// fallback: out[b,:] = f[target_nodes[b],:] when has_edge[b] <= 0
//
// Layout (round 6 = round 5 + XCD-aware contiguous-chunk block swizzle):
//  - float4 per lane, 32-lane half-wave per row => one wave handles TWO rows
//  - branch-free counted loop (round-2 win)
//  - T1 swizzle (bijective, m204): XCD k processes a CONTIGUOUS row chunk.
//    Edges are local (offsets < 200), so each XCD's gather window is ~1.15 MB
//    -> fits its 4 MiB L2. Moves ~250 MB of gather traffic from L3 to L2.

typedef float vfloat4 __attribute__((ext_vector_type(4)));

__global__ __launch_bounds__(256) void tmp_aggregate_kernel(
    const float*  __restrict__ features,      // [N, 128]
    const int*    __restrict__ target_nodes,  // [B]
    const int*    __restrict__ comb_idx,      // [B, cmax, 2]
    const float*  __restrict__ comb_w,        // [B, cmax]
    const float*  __restrict__ has_edge,      // [B]
    float*        __restrict__ out,           // [B, 128]
    int B, int cmax)
{
    // --- XCD-aware bijective swizzle: hardware round-robins blockIdx across 8
    //     XCDs; remap so XCD k gets a contiguous range of logical blocks ---
    const int nwg = gridDim.x;
    const int xcd = blockIdx.x & 7;
    const int j   = blockIdx.x >> 3;
    const int q   = nwg >> 3, r = nwg & 7;
    const int lb  = (xcd < r ? xcd * (q + 1) : r * (q + 1) + (xcd - r) * q) + j;

    const int lane    = threadIdx.x & 63;
    const int wave    = __builtin_amdgcn_readfirstlane((int)(threadIdx.x >> 6));
    const int sub     = lane & 31;            // lane within half-wave
    const int half    = lane >> 5;            // 0 -> row b0, 1 -> row b1
    const int rowbase = (lb * 4 + wave) * 2;
    const int b       = rowbase + half;
    if (rowbase >= B) return;                 // B even; both rows valid together

    const vfloat4* __restrict__ f4 = (const vfloat4*)features;
    const long base = (long)b * cmax;

    // --- per-row live-combo count (w != 0), padding is tail-contiguous ---
    int cnt = 0;
    for (int c0 = 0; c0 < cmax; c0 += 32) {
        const int c = c0 + sub;
        const float w = (c < cmax) ? comb_w[base + c] : 0.0f;
        const unsigned long long m = __ballot(w != 0.0f);
        cnt += __popc((unsigned int)(m >> (half * 32)));
        const bool tail0 = ((unsigned int)(m      ) != 0xffffffffu);
        const bool tail1 = ((unsigned int)(m >> 32) != 0xffffffffu);
        if (tail0 && tail1) break;            // both rows found their tail
    }

    // wave-uniform loop bound = max over the two half-waves
    const int cnt_other = __shfl(cnt, lane ^ 32);
    const int loop_n = __builtin_amdgcn_readfirstlane(cnt > cnt_other ? cnt : cnt_other);

    const int tnode = target_nodes[b];
    const vfloat4 ft = f4[(long)tnode * 32 + sub];

    // --- branch-free main loop: 2 rows in flight per wave ---
    vfloat4 acc = {0.f, 0.f, 0.f, 0.f};
    const int2* __restrict__ idx2 = (const int2*)comb_idx;

    #pragma unroll 4
    for (int c = 0; c < loop_n; ++c) {
        const float w  = comb_w[base + c];            // broadcast within half-wave
        const int2  ix = idx2[base + c];
        const vfloat4 x = f4[(long)ix.x * 32 + sub];
        const vfloat4 y = f4[(long)ix.y * 32 + sub];
        acc.x = fmaf(w * x.x, y.x, acc.x);
        acc.y = fmaf(w * x.y, y.y, acc.y);
        acc.z = fmaf(w * x.z, y.z, acc.z);
        acc.w = fmaf(w * x.w, y.w, acc.w);
    }

    const bool fb = !(has_edge[b] > 0.f);
    acc.x = fb ? ft.x : acc.x;
    acc.y = fb ? ft.y : acc.y;
    acc.z = fb ? ft.z : acc.z;
    acc.w = fb ? ft.w : acc.w;

    __builtin_nontemporal_store(acc, &((vfloat4*)out)[(long)b * 32 + sub]);
}

extern "C" void kernel_launch(void* const* d_in, const int* in_sizes, int n_in,
                              void* d_out, int out_size, void* d_ws, size_t ws_size,
                              hipStream_t stream) {
    const float* features     = (const float*)d_in[0];
    const int*   target_nodes = (const int*)d_in[1];
    const int*   comb_idx     = (const int*)d_in[2];
    const float* comb_w       = (const float*)d_in[3];
    const float* has_edge     = (const float*)d_in[4];
    float*       out          = (float*)d_out;

    const int B    = in_sizes[1];                 // 16384
    const int cmax = in_sizes[2] / (B * 2);       // combos per row (padded)

    const int rows_per_block = 8;                 // 4 waves x 2 rows
    const int grid = (B + rows_per_block - 1) / rows_per_block;

    tmp_aggregate_kernel<<<grid, 256, 0, stream>>>(
        features, target_nodes, comb_idx, comb_w, has_edge, out, B, cmax);
}